// Round 6
// baseline (41.353 us; speedup 1.0000x reference)
//
#include <hip/hip_runtime.h>

// BidPrefix: per row of inputs[B, 302]:
//   rates = row[0:300]; bid = (int)row[300]; mp = (int)row[301]
//   cpz[k] = prod(rates[0:k]); out[row] = { cpz[bid], cpz[mp+1], cpz[mp] }
//
// One wave64 per 4-row slab (4832 B, 16B-aligned since 4832 = 16*302).
// Single memory phase: 5 unconditional float4 wave-loads stream the whole
// slab into private LDS (lane-stride == access size == 16B, perfectly
// coalesced, zero divergence). bid/mp are read back from LDS (cols 300/301
// live inside the slab) -> no separate index load, no dependent HBM
// round-trip. Evidence from R2-R4: per-lane tail-skip did NOT reduce wall
// time (dur == full-fetch BW roofline) -> dropped for a clean max-efficiency
// stream.
// Scan: lane l owns contiguous seg [5l,5l+5) (LDS banks 2-way = free),
// in-register segment prefixes + 6-step DPP multiplicative scan (VALU pipe,
// zero DS cross-lane traffic), wave-uniform queries via v_readlane.
// No __syncthreads anywhere (slabs are wave-private).

constexpr int SEQ   = 300;
constexpr int NCOL  = 302;
constexpr int RPW   = 4;               // rows per wave-slab
constexpr int WPB   = 4;               // waves per block
constexpr int SLABF = NCOL * RPW;      // 1208 floats per slab

template <int CTRL, int ROW_MASK>
__device__ __forceinline__ float mul_scan_step(float run) {
    // t = DPP-moved 'run'; lanes with no valid source (or masked rows) get 1.0
    const int t = __builtin_amdgcn_update_dpp(
        __float_as_int(1.0f), __float_as_int(run), CTRL, ROW_MASK, 0xf, false);
    return run * __int_as_float(t);
}

__global__ __launch_bounds__(256) void bidprefix_kernel(
    const float* __restrict__ in, float* __restrict__ out, int batch)
{
    __shared__ __align__(16) float lds[WPB * SLABF + 32]; // +pad: lanes 60-63 overread

    const int lane = threadIdx.x & 63;
    const int wid  = threadIdx.x >> 6;
    const int row0 = (blockIdx.x * WPB + wid) * RPW;
    if (row0 >= batch) return;

    float* sl = lds + wid * SLABF;
    const float* g = in + (size_t)row0 * NCOL;

    // ---- Single phase: stream slab -> LDS, all loads in flight together ----
    float4 vv[5];
    #pragma unroll
    for (int c = 0; c < 5; ++c) {
        const int f = 256 * c + 4 * lane;             // dword index in slab
        const int a = (f < SLABF) ? f : 0;            // c==4, lane>=46: clamp
        vv[c] = *reinterpret_cast<const float4*>(g + a);
    }
    #pragma unroll
    for (int c = 0; c < 5; ++c) {
        const int f = 256 * c + 4 * lane;
        if (f < SLABF) *reinterpret_cast<float4*>(sl + f) = vv[c];
    }

    // ---- Per-row DPP scan + scalar gathers + store ----
    const int base = 5 * lane;
    #pragma unroll
    for (int r = 0; r < RPW; ++r) {
        const float* rs = sl + r * NCOL;

        // Indices live in the slab (cols 300,301); broadcast LDS read.
        const float2 bm = *reinterpret_cast<const float2*>(rs + SEQ);
        const int bid = __builtin_amdgcn_readfirstlane((int)bm.x);
        const int mp  = __builtin_amdgcn_readfirstlane((int)bm.y);

        const float x0 = rs[base + 0];
        const float x1 = rs[base + 1];
        const float x2 = rs[base + 2];
        const float x3 = rs[base + 3];
        const float x4 = rs[base + 4];

        const float q1 = x0;
        const float q2 = q1 * x1;
        const float q3 = q2 * x2;
        const float q4 = q3 * x3;
        const float q5 = q4 * x4;

        // Inclusive multiplicative scan over 64 lanes, all on the VALU pipe.
        float run = q5;
        run = mul_scan_step<0x111, 0xf>(run);   // row_shr:1
        run = mul_scan_step<0x112, 0xf>(run);   // row_shr:2
        run = mul_scan_step<0x114, 0xf>(run);   // row_shr:4
        run = mul_scan_step<0x118, 0xf>(run);   // row_shr:8
        run = mul_scan_step<0x142, 0xa>(run);   // row_bcast15 -> rows 1,3
        run = mul_scan_step<0x143, 0xc>(run);   // row_bcast31 -> rows 2,3

        const int idxs[3] = { bid, mp + 1, mp };
        float o[3];
        #pragma unroll
        for (int j = 0; j < 3; ++j) {
            const int idx = idxs[j];             // wave-uniform (SGPR)
            const int b   = idx / 5;             // scalar magic-mul
            const int rm  = idx - 5 * b;
            const float qsel = (rm == 0) ? 1.f
                             : (rm == 1) ? q1
                             : (rm == 2) ? q2
                             : (rm == 3) ? q3
                             :             q4;
            const float seg = __int_as_float(
                __builtin_amdgcn_readlane(__float_as_int(qsel), b));
            const int   bp  = (b > 0) ? (b - 1) : 0;
            const float pre = __int_as_float(
                __builtin_amdgcn_readlane(__float_as_int(run), bp));
            o[j] = (b > 0 ? pre : 1.f) * seg;    // cpz[idx]
        }

        if (lane < 3) {
            const float ov = (lane == 0) ? o[0] : (lane == 1) ? o[1] : o[2];
            out[(size_t)(row0 + r) * 3 + lane] = ov;
        }
    }
}

extern "C" void kernel_launch(void* const* d_in, const int* in_sizes, int n_in,
                              void* d_out, int out_size, void* d_ws, size_t ws_size,
                              hipStream_t stream) {
    const float* in = (const float*)d_in[0];
    float* out      = (float*)d_out;
    const int batch = in_sizes[0] / NCOL;             // 200000

    const int rows_per_block = WPB * RPW;             // 16
    dim3 block(256);
    dim3 grid((batch + rows_per_block - 1) / rows_per_block);
    bidprefix_kernel<<<grid, block, 0, stream>>>(in, out, batch);
}

// Round 7
// 33.352 us; speedup vs baseline: 1.2399x; 1.2399x over previous
//
#include <hip/hip_runtime.h>

// BidPrefix: per row of inputs[B, 302]:
//   rates = row[0:300]; bid = (int)row[300]; mp = (int)row[301]
//   cpz[k] = prod(rates[0:k]); out[row] = { cpz[bid], cpz[mp+1], cpz[mp] }
//
// ZERO-LDS version. One wave64 per 4 rows. 300 = 75*4, so a 4-floats-per-
// lane layout needs no re-layout at all:
//   chunk A: cols [0,256)   -> lane l owns float4 [4l, 4l+4)   (64 lanes)
//   chunk B: cols [256,300) -> lane l owns float4 [256+4l, ..) (lanes 0..10)
// Both loads are perfectly coalesced (lane-stride == 16B). Tail-skip kept
// (R5 proved it's worth ~14%): lanes whose float4 lies fully beyond
// maxidx = max(bid, mp+1) clamp their address to the row start (L1-resident
// line, no extra HBM traffic). Garbage in skipped/idle lanes propagates only
// UPWARD in the scan; every queried lane (<= idx/4) is clean, and queries
// with idx >= 256 imply maxidx >= 256 so totalA is clean too.
// Scan: lane-local 4-elem prefixes + 6-step DPP multiplicative scan (VALU
// pipe) for A; 4-step DPP scan for B (11 lanes, single DPP row). Queries are
// wave-uniform -> scalar b = idx>>2, rm = idx&3, gathers via v_readlane.
// No LDS, no __syncthreads, no ds_* at all.

constexpr int SEQ  = 300;
constexpr int NCOL = 302;
constexpr int RPW  = 4;                // rows per wave
constexpr int WPB  = 4;                // waves per block

template <int CTRL, int ROW_MASK>
__device__ __forceinline__ float mul_scan_step(float run) {
    // DPP-move 'run'; lanes with no valid source (or masked rows) get 1.0
    const int t = __builtin_amdgcn_update_dpp(
        __float_as_int(1.0f), __float_as_int(run), CTRL, ROW_MASK, 0xf, false);
    return run * __int_as_float(t);
}

__global__ __launch_bounds__(256) void bidprefix_kernel(
    const float* __restrict__ in, float* __restrict__ out, int batch)
{
    const int lane = threadIdx.x & 63;
    const int wid  = threadIdx.x >> 6;
    const int row0 = (blockIdx.x * WPB + wid) * RPW;
    if (row0 >= batch) return;

    const float* g = in + (size_t)row0 * NCOL;

    // ---- Phase 1: one dwordx2 covers all 4 rows' (bid,mp) ----
    const float2 bmv = *reinterpret_cast<const float2*>(g + (lane & 3) * NCOL + SEQ);
    const int ibv = (int)bmv.x;
    const int imv = (int)bmv.y;
    int bid[RPW], mp[RPW], mx[RPW];
    #pragma unroll
    for (int r = 0; r < RPW; ++r) {
        bid[r] = __builtin_amdgcn_readlane(ibv, r);
        mp[r]  = __builtin_amdgcn_readlane(imv, r);
        mx[r]  = max(bid[r], mp[r] + 1);     // #rates needed (<= 300)
    }

    // ---- Phase 2: all 8 bulk loads in flight together (skip-clamped) ----
    float4 A[RPW], B[RPW];
    #pragma unroll
    for (int r = 0; r < RPW; ++r) {
        const float* gr = g + r * NCOL;
        const int fa = 4 * lane;                       // cols [4l, 4l+4)
        A[r] = *reinterpret_cast<const float4*>(gr + ((fa < mx[r]) ? fa : 0));
        const int fb = 256 + 4 * lane;                 // lanes 0..10 useful
        const bool nb = (lane < 11) && (fb < mx[r]);
        B[r] = *reinterpret_cast<const float4*>(gr + (nb ? fb : 0));
    }

    // ---- Phase 3: per-row DPP scans + scalar gathers + store ----
    #pragma unroll
    for (int r = 0; r < RPW; ++r) {
        // chunk A: lane-local prefixes + 64-lane multiplicative scan
        const float pa1 = A[r].x;
        const float pa2 = pa1 * A[r].y;
        const float pa3 = pa2 * A[r].z;
        const float pa4 = pa3 * A[r].w;
        float runA = pa4;
        runA = mul_scan_step<0x111, 0xf>(runA);   // row_shr:1
        runA = mul_scan_step<0x112, 0xf>(runA);   // row_shr:2
        runA = mul_scan_step<0x114, 0xf>(runA);   // row_shr:4
        runA = mul_scan_step<0x118, 0xf>(runA);   // row_shr:8
        runA = mul_scan_step<0x142, 0xa>(runA);   // row_bcast15 -> rows 1,3
        runA = mul_scan_step<0x143, 0xc>(runA);   // row_bcast31 -> rows 2,3
        const float totalA = __int_as_float(
            __builtin_amdgcn_readlane(__float_as_int(runA), 63));

        // chunk B: lanes 0..10, single DPP row -> 4 row_shr steps suffice
        const float pb1 = B[r].x;
        const float pb2 = pb1 * B[r].y;
        const float pb3 = pb2 * B[r].z;
        const float pb4 = pb3 * B[r].w;
        float runB = pb4;
        runB = mul_scan_step<0x111, 0xf>(runB);   // row_shr:1
        runB = mul_scan_step<0x112, 0xf>(runB);   // row_shr:2
        runB = mul_scan_step<0x114, 0xf>(runB);   // row_shr:4
        runB = mul_scan_step<0x118, 0xf>(runB);   // row_shr:8

        const int idxs[3] = { bid[r], mp[r] + 1, mp[r] };
        float o[3];
        #pragma unroll
        for (int j = 0; j < 3; ++j) {
            const int idx = idxs[j];               // wave-uniform (SGPR)
            float res;
            if (idx < 256) {
                const int bq = idx >> 2;
                const int rm = idx & 3;
                const float qsel = (rm == 0) ? 1.f
                                 : (rm == 1) ? pa1
                                 : (rm == 2) ? pa2
                                 :             pa3;
                const float seg = __int_as_float(
                    __builtin_amdgcn_readlane(__float_as_int(qsel), bq));
                const float pre = (bq > 0)
                    ? __int_as_float(__builtin_amdgcn_readlane(
                          __float_as_int(runA), bq - 1))
                    : 1.f;
                res = pre * seg;
            } else {
                const int t  = idx - 256;
                const int bq = t >> 2;              // 0..11
                const int rm = t & 3;
                const float qsel = (rm == 0) ? 1.f
                                 : (rm == 1) ? pb1
                                 : (rm == 2) ? pb2
                                 :             pb3;
                const float seg = __int_as_float(
                    __builtin_amdgcn_readlane(__float_as_int(qsel), bq));
                const float pre = (bq > 0)
                    ? __int_as_float(__builtin_amdgcn_readlane(
                          __float_as_int(runB), bq - 1))
                    : 1.f;
                res = totalA * pre * seg;
            }
            o[j] = res;                             // cpz[idx]
        }

        if (lane < 3) {
            const float ov = (lane == 0) ? o[0] : (lane == 1) ? o[1] : o[2];
            out[(size_t)(row0 + r) * 3 + lane] = ov;
        }
    }
}

extern "C" void kernel_launch(void* const* d_in, const int* in_sizes, int n_in,
                              void* d_out, int out_size, void* d_ws, size_t ws_size,
                              hipStream_t stream) {
    const float* in = (const float*)d_in[0];
    float* out      = (float*)d_out;
    const int batch = in_sizes[0] / NCOL;             // 200000

    const int rows_per_block = WPB * RPW;             // 16
    dim3 block(256);
    dim3 grid((batch + rows_per_block - 1) / rows_per_block);
    bidprefix_kernel<<<grid, block, 0, stream>>>(in, out, batch);
}